// Round 1
// baseline (1096.846 us; speedup 1.0000x reference)
//
#include <hip/hip_runtime.h>
#include <math.h>

using short8  = __attribute__((ext_vector_type(8))) short;
using floatx4 = __attribute__((ext_vector_type(4))) float;

__device__ __forceinline__ short f2bf(float f) {
  unsigned u = __builtin_bit_cast(unsigned, f);
  u = (u + 0x7fffu + ((u >> 16) & 1u)) >> 16;
  return (short)u;
}

// C[M,N] = A[M,K](lda) @ W[K,N](ldw) + bias;  M%64==0, N%64==0, K%32==0
__global__ __launch_bounds__(256) void gemm_bias(
    const float* __restrict__ A, int lda,
    const float* __restrict__ W, int ldw,
    const float* __restrict__ bias,
    float* __restrict__ C, int ldc,
    int K)
{
  __shared__ short As[64][40];
  __shared__ short Bs[64][40];
  const int tid  = threadIdx.x;
  const int wid  = tid >> 6;
  const int lane = tid & 63;
  const int quad = lane >> 4;
  const int l16  = lane & 15;
  const int bm = blockIdx.x * 64;
  const int bn = blockIdx.y * 64;
  const int wm = (wid & 1) * 32;
  const int wn = (wid >> 1) * 32;

  floatx4 acc[2][2] = {};

  const int ar  = tid >> 2;         // 0..63  A row in tile
  const int ac  = (tid & 3) << 3;   // 0,8,16,24  A col start
  const int bn_ = tid & 63;         // B col in tile
  const int bk0 = (tid >> 6) << 3;  // 0,8,16,24  B k start
  const float* aRow = A + (size_t)(bm + ar) * lda + ac;
  const float* bCol = W + (size_t)bk0 * ldw + bn + bn_;

  for (int k0 = 0; k0 < K; k0 += 32) {
    const float4 av0 = *(const float4*)(aRow + k0);
    const float4 av1 = *(const float4*)(aRow + k0 + 4);
    short8 a16;
    a16[0]=f2bf(av0.x); a16[1]=f2bf(av0.y); a16[2]=f2bf(av0.z); a16[3]=f2bf(av0.w);
    a16[4]=f2bf(av1.x); a16[5]=f2bf(av1.y); a16[6]=f2bf(av1.z); a16[7]=f2bf(av1.w);

    const float* bp = bCol + (size_t)k0 * ldw;
    float bv[8];
#pragma unroll
    for (int j = 0; j < 8; j++) { bv[j] = *bp; bp += ldw; }
    short8 b16;
#pragma unroll
    for (int j = 0; j < 8; j++) b16[j] = f2bf(bv[j]);

    *(short8*)&As[ar][ac]   = a16;
    *(short8*)&Bs[bn_][bk0] = b16;
    __syncthreads();

    short8 af[2], bf[2];
#pragma unroll
    for (int i = 0; i < 2; i++) af[i] = *(const short8*)&As[wm + i*16 + l16][quad*8];
#pragma unroll
    for (int j = 0; j < 2; j++) bf[j] = *(const short8*)&Bs[wn + j*16 + l16][quad*8];
#pragma unroll
    for (int i = 0; i < 2; i++)
#pragma unroll
      for (int j = 0; j < 2; j++)
        acc[i][j] = __builtin_amdgcn_mfma_f32_16x16x32_bf16(af[i], bf[j], acc[i][j], 0, 0, 0);
    __syncthreads();
  }

#pragma unroll
  for (int i = 0; i < 2; i++) {
#pragma unroll
    for (int j = 0; j < 2; j++) {
      const int colg = bn + wn + j*16 + l16;
      const float bb = bias ? bias[colg] : 0.f;
#pragma unroll
      for (int r = 0; r < 4; r++) {
        const int rowg = bm + wm + i*16 + quad*4 + r;
        C[(size_t)rowg * ldc + colg] = acc[i][j][r] + bb;
      }
    }
  }
}

// One wave per row over N=512.
// val = P            (R==null, Mg==null)
// val = R + P        (R!=null, Mg==null)
// val = R + sigmoid(P)*Mg   (Mg!=null)
// out = LN(val; gamma,beta) [optionally GELU]
__global__ __launch_bounds__(256) void row_ln(
    const float* __restrict__ P, int ldp,
    const float* __restrict__ R, int ldr,
    const float* __restrict__ Mg, int ldm,
    const float* __restrict__ gamma, const float* __restrict__ beta,
    float* __restrict__ out, int ldo, int gelu)
{
  const int wid  = threadIdx.x >> 6;
  const int lane = threadIdx.x & 63;
  const int row  = blockIdx.x * 4 + wid;
  const float* p = P + (size_t)row * ldp;
  float v[8], s = 0.f, ss = 0.f;
#pragma unroll
  for (int j = 0; j < 8; j++) {
    const int c = lane + j * 64;
    float x = p[c];
    if (Mg) {
      const float g = 1.f / (1.f + expf(-x));
      x = R[(size_t)row * ldr + c] + g * Mg[(size_t)row * ldm + c];
    } else if (R) {
      x += R[(size_t)row * ldr + c];
    }
    v[j] = x; s += x; ss += x * x;
  }
#pragma unroll
  for (int off = 32; off > 0; off >>= 1) {
    s  += __shfl_xor(s,  off, 64);
    ss += __shfl_xor(ss, off, 64);
  }
  const float mean = s * (1.f / 512.f);
  const float var  = ss * (1.f / 512.f) - mean * mean;
  const float rstd = rsqrtf(var + 1e-5f);
#pragma unroll
  for (int j = 0; j < 8; j++) {
    const int c = lane + j * 64;
    float y = gamma[c] * ((v[j] - mean) * rstd) + beta[c];
    if (gelu) y = 0.5f * y * (1.f + erff(y * 0.70710678118f));
    out[(size_t)row * ldo + c] = y;
  }
}

// logit projection: GELU(LN(sigmoid(x) @ W + b)); N=256, one wave per row
__global__ __launch_bounds__(256) void lproj(
    const float* __restrict__ logits, int F,
    const float* __restrict__ W, const float* __restrict__ bias,
    const float* __restrict__ gamma, const float* __restrict__ beta,
    float* __restrict__ out, int ldo)
{
  const int wid  = threadIdx.x >> 6;
  const int lane = threadIdx.x & 63;
  const int row  = blockIdx.x * 4 + wid;
  float sg[16];
  for (int f = 0; f < F; f++)
    sg[f] = 1.f / (1.f + expf(-logits[(size_t)row * F + f]));
  float v[4], s = 0.f, ss = 0.f;
#pragma unroll
  for (int j = 0; j < 4; j++) {
    const int c = lane + j * 64;
    float a = bias[c];
    for (int f = 0; f < F; f++) a += sg[f] * W[f * 256 + c];
    v[j] = a; s += a; ss += a * a;
  }
#pragma unroll
  for (int off = 32; off > 0; off >>= 1) {
    s  += __shfl_xor(s,  off, 64);
    ss += __shfl_xor(ss, off, 64);
  }
  const float mean = s * (1.f / 256.f);
  const float var  = ss * (1.f / 256.f) - mean * mean;
  const float rstd = rsqrtf(var + 1e-5f);
#pragma unroll
  for (int j = 0; j < 4; j++) {
    const int c = lane + j * 64;
    float y = gamma[c] * ((v[j] - mean) * rstd) + beta[c];
    y = 0.5f * y * (1.f + erff(y * 0.70710678118f));
    out[(size_t)row * ldo + c] = y;
  }
}

// cat[:,0:512]=e ; cat[:,512:1024]=0.5*(a+b)
__global__ __launch_bounds__(256) void combine(
    const float* __restrict__ e, const float* __restrict__ a,
    const float* __restrict__ b, float* __restrict__ cat)
{
  const size_t i = (size_t)blockIdx.x * 256 + threadIdx.x;   // over 8192*128 float4s
  const float4 ev = ((const float4*)e)[i];
  const float4 av = ((const float4*)a)[i];
  const float4 bv = ((const float4*)b)[i];
  const size_t row = i >> 7, col = i & 127;
  float4* catRow = (float4*)cat + row * 256;
  catRow[col] = ev;
  float4 m;
  m.x = 0.5f*(av.x+bv.x); m.y = 0.5f*(av.y+bv.y);
  m.z = 0.5f*(av.z+bv.z); m.w = 0.5f*(av.w+bv.w);
  catRow[128 + col] = m;
}

// cb = bv @ Wo + bo   (512-vec @ 512x512)
__global__ __launch_bounds__(256) void bias_combine(
    const float* __restrict__ bv, const float* __restrict__ Wo,
    const float* __restrict__ bo, float* __restrict__ cbout)
{
  const int n = blockIdx.x * 256 + threadIdx.x;
  float a = bo[n];
  for (int k = 0; k < 512; k++) a += bv[k] * Wo[k * 512 + n];
  cbout[n] = a;
}

extern "C" void kernel_launch(void* const* d_in, const int* in_sizes, int n_in,
                              void* d_out, int out_size, void* d_ws, size_t ws_size,
                              hipStream_t stream)
{
  const float* verb_hidden   = (const float*)d_in[0];
  const float* verb_logits   = (const float*)d_in[1];
  const float* inst_hidden   = (const float*)d_in[2];
  const float* inst_logits   = (const float*)d_in[3];
  const float* target_hidden = (const float*)d_in[4];
  const float* target_logits = (const float*)d_in[5];
  const float* hp_W  = (const float*)d_in[6];
  const float* hp_b  = (const float*)d_in[7];
  const float* hp_g  = (const float*)d_in[8];
  const float* hp_be = (const float*)d_in[9];
  const float* lp_W_verb   = (const float*)d_in[10];
  const float* lp_b_verb   = (const float*)d_in[11];
  const float* lp_W_inst   = (const float*)d_in[12];
  const float* lp_b_inst   = (const float*)d_in[13];
  const float* lp_W_target = (const float*)d_in[14];
  const float* lp_b_target = (const float*)d_in[15];
  const float* lp_g  = (const float*)d_in[16];
  const float* lp_be = (const float*)d_in[17];
  const float* mha_in_W  = (const float*)d_in[18];
  const float* mha_in_b  = (const float*)d_in[19];
  const float* mha_out_W = (const float*)d_in[20];
  const float* mha_out_b = (const float*)d_in[21];
  const float* n1_g  = (const float*)d_in[22];
  const float* n1_be = (const float*)d_in[23];
  const float* n2_g  = (const float*)d_in[24];
  const float* n2_be = (const float*)d_in[25];
  const float* gate_W = (const float*)d_in[26];
  const float* gate_b = (const float*)d_in[27];
  const float* fus_W1 = (const float*)d_in[28];
  const float* fus_b1 = (const float*)d_in[29];
  const float* fus_g1 = (const float*)d_in[30];
  const float* fus_ge1= (const float*)d_in[31];
  const float* fus_W2 = (const float*)d_in[32];
  const float* fus_b2 = (const float*)d_in[33];
  const float* fus_g2 = (const float*)d_in[34];
  const float* fus_ge2= (const float*)d_in[35];

  float* ws = (float*)d_ws;
  const size_t S = (size_t)8192 * 512;
  float* h0 = ws;      float* h1 = h0 + S;  float* h2 = h1 + S;
  float* e0 = h2 + S;  float* e1 = e0 + S;  float* e2 = e1 + S;
  float* comb = e2 + S;                          // 8192*2304
  float* cat  = comb + (size_t)8192 * 2304;      // 8192*1024 (doubles as 2x preact scratch)
  float* cA   = cat + (size_t)8192 * 1024;
  float* cB   = cA + S;
  float* CW   = cB + S;                          // 4*512*512 folded attn weights
  float* cb   = CW + (size_t)4 * 512 * 512;      // 4*512 folded attn biases

  float* P1 = cat;        // scratch preact (B x 512)
  float* P2 = cat + S;    // second scratch preact

  dim3 blk(256);
  dim3 gMain(128, 8);   // M=8192, N=512
  dim3 gW(8, 8);        // M=512,  N=512

  // Fold each MHA module: CW_i = Wv_i @ Wo_i ; cb_i = bv_i @ Wo_i + bo_i
  for (int i = 0; i < 4; i++) {
    gemm_bias<<<gW, blk, 0, stream>>>(
        mha_in_W + (size_t)i*512*1536 + 1024, 1536,
        mha_out_W + (size_t)i*512*512, 512,
        nullptr, CW + (size_t)i*512*512, 512, 512);
    bias_combine<<<dim3(2), blk, 0, stream>>>(
        mha_in_b + i*1536 + 1024, mha_out_W + (size_t)i*512*512,
        mha_out_b + i*512, cb + i*512);
  }

  const float* xs[3] = {verb_hidden, inst_hidden, target_hidden};
  float* hs[3] = {h0, h1, h2};
  float* es[3] = {e0, e1, e2};

  // Stage A: h_t = GELU(LN(x_t @ hp_W[t] + hp_b[t]))
  for (int t = 0; t < 3; t++) {
    gemm_bias<<<gMain, blk, 0, stream>>>(xs[t], 1024,
        hp_W + (size_t)t*1024*512, 512, hp_b + t*512, P1, 512, 1024);
    row_ln<<<2048, blk, 0, stream>>>(P1, 512, nullptr, 0, nullptr, 0,
        hp_g + t*512, hp_be + t*512, hs[t], 512, 1);
  }

  // Stage B: logit projections -> comb cols 1536.., 1792.., 2048..
  lproj<<<2048, blk, 0, stream>>>(verb_logits, 10, lp_W_verb, lp_b_verb,
      lp_g + 0,   lp_be + 0,   comb + 1536, 2304);
  lproj<<<2048, blk, 0, stream>>>(inst_logits, 6, lp_W_inst, lp_b_inst,
      lp_g + 256, lp_be + 256, comb + 1792, 2304);
  lproj<<<2048, blk, 0, stream>>>(target_logits, 15, lp_W_target, lp_b_target,
      lp_g + 512, lp_be + 512, comb + 2048, 2304);

  // Stage C: e_t = LN(h_t + h_t @ CW0 + cb0)
  for (int t = 0; t < 3; t++) {
    gemm_bias<<<gMain, blk, 0, stream>>>(hs[t], 512, CW, 512, cb, P2, 512, 512);
    row_ln<<<2048, blk, 0, stream>>>(P2, 512, hs[t], 512, nullptr, 0,
        n1_g + t*512, n1_be + t*512, es[t], 512, 0);
  }

  // Stage D+E: cross attn pairs, gate, fuse -> comb cols t*512
  const int mods[3][2] = {{1,2},{1,3},{2,3}};
  const int srcs[3][2] = {{1,2},{0,2},{0,1}};
  for (int t = 0; t < 3; t++) {
    gemm_bias<<<gMain, blk, 0, stream>>>(es[srcs[t][0]], 512,
        CW + (size_t)mods[t][0]*512*512, 512, cb + mods[t][0]*512, cA, 512, 512);
    gemm_bias<<<gMain, blk, 0, stream>>>(es[srcs[t][1]], 512,
        CW + (size_t)mods[t][1]*512*512, 512, cb + mods[t][1]*512, cB, 512, 512);
    combine<<<4096, blk, 0, stream>>>(es[t], cA, cB, cat);
    gemm_bias<<<gMain, blk, 0, stream>>>(cat, 1024,
        gate_W + (size_t)t*1024*512, 512, gate_b + t*512, cA, 512, 1024);
    row_ln<<<2048, blk, 0, stream>>>(cA, 512, es[t], 512, cat + 512, 1024,
        n2_g + t*512, n2_be + t*512, comb + t*512, 2304, 0);
  }

  // Stage F: fusion head
  gemm_bias<<<gMain, blk, 0, stream>>>(comb, 2304, fus_W1, 512, fus_b1, cA, 512, 2304);
  row_ln<<<2048, blk, 0, stream>>>(cA, 512, nullptr, 0, nullptr, 0,
      fus_g1, fus_ge1, cB, 512, 1);
  gemm_bias<<<gMain, blk, 0, stream>>>(cB, 512, fus_W2, 512, fus_b2, cA, 512, 512);
  row_ln<<<2048, blk, 0, stream>>>(cA, 512, nullptr, 0, nullptr, 0,
      fus_g2, fus_ge2, (float*)d_out, 512, 0);
}

// Round 2
// 777.041 us; speedup vs baseline: 1.4116x; 1.4116x over previous
//
#include <hip/hip_runtime.h>
#include <math.h>

typedef unsigned short ushort_t;
using short8  = __attribute__((ext_vector_type(8))) short;
using floatx4 = __attribute__((ext_vector_type(4))) float;

__device__ __forceinline__ ushort_t f2bf(float f) {
  unsigned u = __builtin_bit_cast(unsigned, f);
  u = (u + 0x7fffu + ((u >> 16) & 1u)) >> 16;
  return (ushort_t)u;
}
__device__ __forceinline__ float bf2f(ushort_t u) {
  unsigned v = ((unsigned)u) << 16;
  return __builtin_bit_cast(float, v);
}

__device__ __forceinline__ void load_lds16(const ushort_t* g, ushort_t* l) {
  __builtin_amdgcn_global_load_lds(
      (const __attribute__((address_space(1))) unsigned int*)g,
      (__attribute__((address_space(3))) unsigned int*)l, 16, 0, 0);
}

// ---------------- GEMM: C[M,512] = A[M,K]bf16 @ W^T  (W stored [N=512,K] bf16) + bias ----------------
struct GemmArgs {
  const ushort_t* A[6]; const ushort_t* W[6]; const float* b[6]; float* C[6];
};

__global__ __launch_bounds__(256) void gemm_bt(GemmArgs ga, int K) {
  const int z = blockIdx.z;
  const ushort_t* __restrict__ A = ga.A[z];
  const ushort_t* __restrict__ W = ga.W[z];
  const float*  __restrict__ bias = ga.b[z];
  float* __restrict__ C = ga.C[z];
  __shared__ ushort_t As[128 * 32];
  __shared__ ushort_t Bs[128 * 32];
  const int tid = threadIdx.x;
  const int wid = tid >> 6, lane = tid & 63, quad = lane >> 4, l16 = lane & 15;
  const int bm = blockIdx.x * 128, bn = blockIdx.y * 128;
  const int wm = (wid & 1) * 64, wn = (wid >> 1) * 64;
  floatx4 acc[4][4] = {};

  const int srow = tid >> 2, scol = (tid & 3) * 8;   // 16B per thread
  const ushort_t* aG = A + (size_t)(bm + srow) * K + scol;
  const ushort_t* bG = W + (size_t)(bn + srow) * K + scol;
  ushort_t* aL = As + tid * 8;    // byte offset tid*16 (lane-contiguous, wave base uniform)
  ushort_t* bL = Bs + tid * 8;
  const size_t rstep = (size_t)64 * K;

  for (int k0 = 0; k0 < K; k0 += 32) {
    __syncthreads();
    load_lds16(aG + k0,         aL);
    load_lds16(aG + k0 + rstep, aL + 2048);
    load_lds16(bG + k0,         bL);
    load_lds16(bG + k0 + rstep, bL + 2048);
    __syncthreads();
    short8 af[4], bf[4];
#pragma unroll
    for (int i = 0; i < 4; i++)
      af[i] = *(const short8*)&As[(wm + 16 * i + l16) * 32 + quad * 8];
#pragma unroll
    for (int j = 0; j < 4; j++)
      bf[j] = *(const short8*)&Bs[(wn + 16 * j + l16) * 32 + quad * 8];
#pragma unroll
    for (int i = 0; i < 4; i++)
#pragma unroll
      for (int j = 0; j < 4; j++)
        acc[i][j] = __builtin_amdgcn_mfma_f32_16x16x32_bf16(af[i], bf[j], acc[i][j], 0, 0, 0);
  }

#pragma unroll
  for (int i = 0; i < 4; i++) {
#pragma unroll
    for (int j = 0; j < 4; j++) {
      const int colg = bn + wn + 16 * j + l16;
      const float bb = bias ? bias[colg] : 0.f;
#pragma unroll
      for (int r = 0; r < 4; r++) {
        const int rowg = bm + wm + 16 * i + quad * 4 + r;
        C[(size_t)rowg * 512 + colg] = acc[i][j][r] + bb;
      }
    }
  }
}

// ---------------- LayerNorm family (N=512), one wave/row ----------------
// modes: PA!=null: val = R + sigmoid(P)*0.5*(PA+PB)   (fuse)
//        else R!=null: val = R + P                    (residual LN)
//        else: val = P
__global__ __launch_bounds__(256) void row_ln(
    const float* __restrict__ P,
    const ushort_t* __restrict__ R,
    const float* __restrict__ PA, const float* __restrict__ PB,
    const float* __restrict__ gamma, const float* __restrict__ beta, int gstride,
    ushort_t* __restrict__ outb, float* __restrict__ outf, int ldo, int gelu)
{
  const int wid = threadIdx.x >> 6, lane = threadIdx.x & 63;
  const int row = blockIdx.x * 4 + wid;
  const int t = row >> 13;
  const float* g  = gamma + t * gstride;
  const float* be = beta + t * gstride;
  const float* p = P + (size_t)row * 512;
  float v[8], s = 0.f, ss = 0.f;
#pragma unroll
  for (int j = 0; j < 8; j++) {
    const int c = lane + j * 64;
    float x = p[c];
    if (PA) {
      const float sg = 1.f / (1.f + expf(-x));
      x = bf2f(R[(size_t)row * 512 + c]) +
          sg * 0.5f * (PA[(size_t)row * 512 + c] + PB[(size_t)row * 512 + c]);
    } else if (R) {
      x += bf2f(R[(size_t)row * 512 + c]);
    }
    v[j] = x; s += x; ss += x * x;
  }
#pragma unroll
  for (int off = 32; off > 0; off >>= 1) {
    s  += __shfl_xor(s,  off, 64);
    ss += __shfl_xor(ss, off, 64);
  }
  const float mean = s * (1.f / 512.f);
  const float var  = ss * (1.f / 512.f) - mean * mean;
  const float rstd = rsqrtf(var + 1e-5f);
#pragma unroll
  for (int j = 0; j < 8; j++) {
    const int c = lane + j * 64;
    float y = g[c] * ((v[j] - mean) * rstd) + be[c];
    if (gelu) y = 0.5f * y * (1.f + erff(y * 0.70710678118f));
    if (outb) outb[(size_t)row * ldo + c] = f2bf(y);
    else      outf[(size_t)row * ldo + c] = y;
  }
}

// ---------------- logit projection: GELU(LN(sigmoid(x) @ W + b)); N=256 ----------------
__global__ __launch_bounds__(256) void lproj(
    const float* __restrict__ logits, int F,
    const float* __restrict__ W, const float* __restrict__ bias,
    const float* __restrict__ gamma, const float* __restrict__ beta,
    ushort_t* __restrict__ out, int ldo)
{
  const int wid = threadIdx.x >> 6, lane = threadIdx.x & 63;
  const int row = blockIdx.x * 4 + wid;
  float sg[16];
  for (int f = 0; f < F; f++)
    sg[f] = 1.f / (1.f + expf(-logits[(size_t)row * F + f]));
  float v[4], s = 0.f, ss = 0.f;
#pragma unroll
  for (int j = 0; j < 4; j++) {
    const int c = lane + j * 64;
    float a = bias[c];
    for (int f = 0; f < F; f++) a += sg[f] * W[f * 256 + c];
    v[j] = a; s += a; ss += a * a;
  }
#pragma unroll
  for (int off = 32; off > 0; off >>= 1) {
    s  += __shfl_xor(s,  off, 64);
    ss += __shfl_xor(ss, off, 64);
  }
  const float mean = s * (1.f / 256.f);
  const float var  = ss * (1.f / 256.f) - mean * mean;
  const float rstd = rsqrtf(var + 1e-5f);
#pragma unroll
  for (int j = 0; j < 4; j++) {
    const int c = lane + j * 64;
    float y = gamma[c] * ((v[j] - mean) * rstd) + beta[c];
    y = 0.5f * y * (1.f + erff(y * 0.70710678118f));
    out[(size_t)row * ldo + c] = f2bf(y);
  }
}

// cat[:,0:512]=e(bf16) ; cat[:,512:1024]=bf16(0.5*(a+b))
__global__ __launch_bounds__(256) void combine(
    const ushort_t* __restrict__ e, const float* __restrict__ a,
    const float* __restrict__ b, ushort_t* __restrict__ cat)
{
  const size_t i = (size_t)blockIdx.x * 256 + threadIdx.x;  // 8192*128 groups of 4
  const size_t row = i >> 7, col = i & 127;
  const ushort4 ev = ((const ushort4*)e)[i];
  const float4 av = ((const float4*)a)[i];
  const float4 bv = ((const float4*)b)[i];
  ushort4 mv;
  mv.x = f2bf(0.5f * (av.x + bv.x)); mv.y = f2bf(0.5f * (av.y + bv.y));
  mv.z = f2bf(0.5f * (av.z + bv.z)); mv.w = f2bf(0.5f * (av.w + bv.w));
  ushort4* catRow = (ushort4*)(cat + row * 1024);
  catRow[col] = ev;
  catRow[128 + col] = mv;
}

// cb_z = bv_z @ Wo_z + bo_z  (f32), grid (2,1,4)
__global__ __launch_bounds__(256) void bias_combine(
    const float* __restrict__ mha_in_b, const float* __restrict__ mha_out_W,
    const float* __restrict__ mha_out_b, float* __restrict__ cb)
{
  const int z = blockIdx.z;
  const float* bv = mha_in_b + z * 1536 + 1024;
  const float* Wo = mha_out_W + (size_t)z * 512 * 512;
  const int n = blockIdx.x * 256 + threadIdx.x;
  float a = mha_out_b[z * 512 + n];
  for (int k = 0; k < 512; k++) a += bv[k] * Wo[k * 512 + n];
  cb[z * 512 + n] = a;
}

// transpose-convert: out_bf16[N,K] = in_f32[K,N];  grid (N/32, K/32, z)
__global__ __launch_bounds__(256) void tconv(
    const float* __restrict__ in, size_t in_z,
    ushort_t* __restrict__ out, size_t out_z, int K, int N)
{
  __shared__ float t[32][33];
  in  += blockIdx.z * in_z;
  out += blockIdx.z * out_z;
  const int n0 = blockIdx.x * 32, k0 = blockIdx.y * 32;
  const int tx = threadIdx.x & 31, ty = threadIdx.x >> 5;  // ty 0..7
#pragma unroll
  for (int r = 0; r < 32; r += 8)
    t[ty + r][tx] = in[(size_t)(k0 + ty + r) * N + n0 + tx];
  __syncthreads();
#pragma unroll
  for (int r = 0; r < 32; r += 8)
    out[(size_t)(n0 + ty + r) * K + k0 + tx] = f2bf(t[tx][ty + r]);
}

// Wv slice convert: out[z][k][j] = bf16(mha_in_W[z][k][1024+j]); grid (1024,1,4)
__global__ __launch_bounds__(256) void conv_wv(const float* __restrict__ in, ushort_t* __restrict__ out) {
  const int z = blockIdx.z;
  const int idx = blockIdx.x * 256 + threadIdx.x;   // 262144 per z
  const int r = idx >> 9, c = idx & 511;
  out[(size_t)z * 262144 + idx] = f2bf(in[(size_t)z * 786432 + (size_t)r * 1536 + 1024 + c]);
}

// plain f32 -> bf16, 4 elems/thread; grid n4/256
__global__ __launch_bounds__(256) void conv_x(const float* __restrict__ in, ushort_t* __restrict__ out) {
  const size_t i = (size_t)blockIdx.x * 256 + threadIdx.x;
  const float4 f = ((const float4*)in)[i];
  ushort4 o;
  o.x = f2bf(f.x); o.y = f2bf(f.y); o.z = f2bf(f.z); o.w = f2bf(f.w);
  ((ushort4*)out)[i] = o;
}

extern "C" void kernel_launch(void* const* d_in, const int* in_sizes, int n_in,
                              void* d_out, int out_size, void* d_ws, size_t ws_size,
                              hipStream_t stream)
{
  const float* verb_hidden   = (const float*)d_in[0];
  const float* verb_logits   = (const float*)d_in[1];
  const float* inst_hidden   = (const float*)d_in[2];
  const float* inst_logits   = (const float*)d_in[3];
  const float* target_hidden = (const float*)d_in[4];
  const float* target_logits = (const float*)d_in[5];
  const float* hp_W  = (const float*)d_in[6];
  const float* hp_b  = (const float*)d_in[7];
  const float* hp_g  = (const float*)d_in[8];
  const float* hp_be = (const float*)d_in[9];
  const float* lp_W_verb   = (const float*)d_in[10];
  const float* lp_b_verb   = (const float*)d_in[11];
  const float* lp_W_inst   = (const float*)d_in[12];
  const float* lp_b_inst   = (const float*)d_in[13];
  const float* lp_W_target = (const float*)d_in[14];
  const float* lp_b_target = (const float*)d_in[15];
  const float* lp_g  = (const float*)d_in[16];
  const float* lp_be = (const float*)d_in[17];
  const float* mha_in_W  = (const float*)d_in[18];
  const float* mha_in_b  = (const float*)d_in[19];
  const float* mha_out_W = (const float*)d_in[20];
  const float* mha_out_b = (const float*)d_in[21];
  const float* n1_g  = (const float*)d_in[22];
  const float* n1_be = (const float*)d_in[23];
  const float* n2_g  = (const float*)d_in[24];
  const float* n2_be = (const float*)d_in[25];
  const float* gate_W = (const float*)d_in[26];
  const float* gate_b = (const float*)d_in[27];
  const float* fus_W1 = (const float*)d_in[28];
  const float* fus_b1 = (const float*)d_in[29];
  const float* fus_g1 = (const float*)d_in[30];
  const float* fus_ge1= (const float*)d_in[31];
  const float* fus_W2 = (const float*)d_in[32];
  const float* fus_b2 = (const float*)d_in[33];
  const float* fus_g2 = (const float*)d_in[34];
  const float* fus_ge2= (const float*)d_in[35];

  char* w = (char*)d_ws;
  const size_t S2 = (size_t)8192 * 512;
  float*    Pbig   = (float*)w;                       // 24576x512 f32   (48 MB)
  ushort_t* xbf    = (ushort_t*)(w + 50331648);       // 3x8192x1024 bf16 (48 MB)
  ushort_t* hbf    = (ushort_t*)(w + 100663296);      // 24576x512 bf16  (24 MB)
  ushort_t* ebf    = (ushort_t*)(w + 125829120);      // 24576x512 bf16  (24 MB)
  ushort_t* catbf  = (ushort_t*)(w + 150994944);      // 8192x1024 bf16  (16 MB)
  ushort_t* combbf = (ushort_t*)(w + 167772160);      // 8192x2304 bf16  (36 MB)
  ushort_t* hpWt   = (ushort_t*)(w + 205520896);      // 3x512x1024
  ushort_t* gateWt = (ushort_t*)(w + 208666624);      // 3x512x1024
  ushort_t* fusW1t = (ushort_t*)(w + 211812352);      // 512x2304
  ushort_t* fusW2t = (ushort_t*)(w + 214171648);      // 512x512
  ushort_t* WoT    = (ushort_t*)(w + 214695936);      // 4x512x512
  ushort_t* Wvbf   = (ushort_t*)(w + 216793088);      // 4x512x512
  float*    CWf32  = (float*)(w + 218890240);         // 4x512x512 f32
  ushort_t* CWt    = (ushort_t*)(w + 223084544);      // 4x512x512
  float*    cb     = (float*)(w + 225181696);         // 4x512 f32

  float* PA = Pbig + S2;
  float* PB = Pbig + 2 * S2;

  dim3 blk(256);

  // ---- conversions ----
  conv_x<<<8192, blk, 0, stream>>>(verb_hidden,   xbf);
  conv_x<<<8192, blk, 0, stream>>>(inst_hidden,   xbf + (size_t)8192 * 1024);
  conv_x<<<8192, blk, 0, stream>>>(target_hidden, xbf + (size_t)2 * 8192 * 1024);
  conv_wv<<<dim3(1024, 1, 4), blk, 0, stream>>>(mha_in_W, Wvbf);
  tconv<<<dim3(16, 32, 3), blk, 0, stream>>>(hp_W,   524288, hpWt,   524288, 1024, 512);
  tconv<<<dim3(16, 32, 3), blk, 0, stream>>>(gate_W, 524288, gateWt, 524288, 1024, 512);
  tconv<<<dim3(16, 72, 1), blk, 0, stream>>>(fus_W1, 0, fusW1t, 0, 2304, 512);
  tconv<<<dim3(16, 16, 1), blk, 0, stream>>>(fus_W2, 0, fusW2t, 0, 512, 512);
  tconv<<<dim3(16, 16, 4), blk, 0, stream>>>(mha_out_W, 262144, WoT, 262144, 512, 512);
  bias_combine<<<dim3(2, 1, 4), blk, 0, stream>>>(mha_in_b, mha_out_W, mha_out_b, cb);

  // ---- fold: CW_z = Wv_z @ Wo_z  (M=512, K=512) ----
  {
    GemmArgs ga{};
    for (int z = 0; z < 4; z++) {
      ga.A[z] = Wvbf + (size_t)z * 262144;
      ga.W[z] = WoT  + (size_t)z * 262144;
      ga.b[z] = nullptr;
      ga.C[z] = CWf32 + (size_t)z * 262144;
    }
    gemm_bt<<<dim3(4, 4, 4), blk, 0, stream>>>(ga, 512);
  }
  tconv<<<dim3(16, 16, 4), blk, 0, stream>>>(CWf32, 262144, CWt, 262144, 512, 512);

  // ---- stage A: h_t = GELU(LN(x_t @ hp_W_t + hp_b_t)) ----
  {
    GemmArgs ga{};
    for (int z = 0; z < 3; z++) {
      ga.A[z] = xbf + (size_t)z * 8192 * 1024;
      ga.W[z] = hpWt + (size_t)z * 524288;
      ga.b[z] = hp_b + z * 512;
      ga.C[z] = Pbig + (size_t)z * S2;
    }
    gemm_bt<<<dim3(64, 4, 3), blk, 0, stream>>>(ga, 1024);
  }
  row_ln<<<6144, blk, 0, stream>>>(Pbig, nullptr, nullptr, nullptr,
      hp_g, hp_be, 512, hbf, nullptr, 512, 1);

  // ---- stage B: logit projections into comb ----
  lproj<<<2048, blk, 0, stream>>>(verb_logits, 10, lp_W_verb, lp_b_verb,
      lp_g + 0,   lp_be + 0,   combbf + 1536, 2304);
  lproj<<<2048, blk, 0, stream>>>(inst_logits, 6, lp_W_inst, lp_b_inst,
      lp_g + 256, lp_be + 256, combbf + 1792, 2304);
  lproj<<<2048, blk, 0, stream>>>(target_logits, 15, lp_W_target, lp_b_target,
      lp_g + 512, lp_be + 512, combbf + 2048, 2304);

  // ---- stage C: e = LN(h + h @ CW0 + cb0), batched M=24576 ----
  {
    GemmArgs ga{};
    ga.A[0] = hbf; ga.W[0] = CWt; ga.b[0] = cb; ga.C[0] = Pbig;
    gemm_bt<<<dim3(192, 4, 1), blk, 0, stream>>>(ga, 512);
  }
  row_ln<<<6144, blk, 0, stream>>>(Pbig, hbf, nullptr, nullptr,
      n1_g, n1_be, 512, ebf, nullptr, 512, 0);

  // ---- stage D/E per task ----
  const int mods[3][2] = {{1, 2}, {1, 3}, {2, 3}};
  const int srcs[3][2] = {{1, 2}, {0, 2}, {0, 1}};
  for (int t = 0; t < 3; t++) {
    GemmArgs ga{};
    for (int u = 0; u < 2; u++) {
      ga.A[u] = ebf + (size_t)srcs[t][u] * S2;
      ga.W[u] = CWt + (size_t)mods[t][u] * 262144;
      ga.b[u] = cb + mods[t][u] * 512;
      ga.C[u] = (u == 0) ? PA : PB;
    }
    gemm_bt<<<dim3(64, 4, 2), blk, 0, stream>>>(ga, 512);
    combine<<<4096, blk, 0, stream>>>(ebf + (size_t)t * S2, PA, PB, catbf);
    GemmArgs gg{};
    gg.A[0] = catbf; gg.W[0] = gateWt + (size_t)t * 524288;
    gg.b[0] = gate_b + t * 512; gg.C[0] = Pbig;
    gemm_bt<<<dim3(64, 4, 1), blk, 0, stream>>>(gg, 1024);
    row_ln<<<2048, blk, 0, stream>>>(Pbig, ebf + (size_t)t * S2, PA, PB,
        n2_g + t * 512, n2_be + t * 512, 0, combbf + t * 512, nullptr, 2304, 0);
  }

  // ---- stage F: fusion head ----
  {
    GemmArgs ga{};
    ga.A[0] = combbf; ga.W[0] = fusW1t; ga.b[0] = fus_b1; ga.C[0] = Pbig;
    gemm_bt<<<dim3(64, 4, 1), blk, 0, stream>>>(ga, 2304);
  }
  row_ln<<<2048, blk, 0, stream>>>(Pbig, nullptr, nullptr, nullptr,
      fus_g1, fus_ge1, 0, catbf, nullptr, 512, 1);
  {
    GemmArgs ga{};
    ga.A[0] = catbf; ga.W[0] = fusW2t; ga.b[0] = fus_b2; ga.C[0] = Pbig;
    gemm_bt<<<dim3(64, 4, 1), blk, 0, stream>>>(ga, 512);
  }
  row_ln<<<2048, blk, 0, stream>>>(Pbig, nullptr, nullptr, nullptr,
      fus_g2, fus_ge2, 0, nullptr, (float*)d_out, 512, 0);
}

// Round 3
// 683.749 us; speedup vs baseline: 1.6042x; 1.1364x over previous
//
#include <hip/hip_runtime.h>
#include <math.h>

typedef unsigned short ushort_t;
using short8  = __attribute__((ext_vector_type(8))) short;
using floatx4 = __attribute__((ext_vector_type(4))) float;

__device__ __forceinline__ ushort_t f2bf(float f) {
  unsigned u = __builtin_bit_cast(unsigned, f);
  u = (u + 0x7fffu + ((u >> 16) & 1u)) >> 16;
  return (ushort_t)u;
}
__device__ __forceinline__ float bf2f(ushort_t u) {
  unsigned v = ((unsigned)u) << 16;
  return __builtin_bit_cast(float, v);
}

__device__ __forceinline__ void load_lds16(const ushort_t* g, ushort_t* l) {
  __builtin_amdgcn_global_load_lds(
      (const __attribute__((address_space(1))) unsigned int*)g,
      (__attribute__((address_space(3))) unsigned int*)l, 16, 0, 0);
}

// ---------------- segmented batched GEMM ----------------
// C[M,512] = sum_s A_s[M,Ks] @ W_s^T  (+bias)*scale ; W_s stored [512,Ks] bf16
struct Seg { const ushort_t* A; const ushort_t* W; int lda, ldw, K; };
struct GemmZ {
  float* C; ushort_t* Cb; const float* bias;
  float scale; int transC; int nseg;
  Seg seg[6];
};
struct GemmArgs { GemmZ z[6]; };

template <int BM>
__global__ __launch_bounds__(256) void gemm_bt(GemmArgs ga) {
  const GemmZ& gz = ga.z[blockIdx.z];
  __shared__ ushort_t As[BM * 32];
  __shared__ ushort_t Bs[128 * 32];
  const int tid = threadIdx.x;
  const int wid = tid >> 6, lane = tid & 63, quad = lane >> 4, l16 = lane & 15;
  const int bm = blockIdx.x * BM, bn = blockIdx.y * 128;
  constexpr int MI = BM / 32;
  const int wm = (wid & 1) * (BM / 2), wn = (wid >> 1) * 64;
  floatx4 acc[MI][4] = {};
  const int srow = tid >> 2, scol = (tid & 3) * 8;
  ushort_t* aL = As + tid * 8;
  ushort_t* bL = Bs + tid * 8;

  for (int s = 0; s < gz.nseg; s++) {
    const Seg sg = gz.seg[s];
    const ushort_t* aG = sg.A + (size_t)(bm + srow) * sg.lda + scol;
    const ushort_t* bG = sg.W + (size_t)(bn + srow) * sg.ldw + scol;
    const size_t astep = (size_t)64 * sg.lda;
    const size_t bstep = (size_t)64 * sg.ldw;
    for (int k0 = 0; k0 < sg.K; k0 += 32) {
      __syncthreads();
      load_lds16(aG + k0, aL);
      if (BM == 128) load_lds16(aG + k0 + astep, aL + 2048);
      load_lds16(bG + k0, bL);
      load_lds16(bG + k0 + bstep, bL + 2048);
      __syncthreads();
      short8 af[MI], bf[4];
#pragma unroll
      for (int i = 0; i < MI; i++)
        af[i] = *(const short8*)&As[(wm + 16 * i + l16) * 32 + quad * 8];
#pragma unroll
      for (int j = 0; j < 4; j++)
        bf[j] = *(const short8*)&Bs[(wn + 16 * j + l16) * 32 + quad * 8];
#pragma unroll
      for (int i = 0; i < MI; i++)
#pragma unroll
        for (int j = 0; j < 4; j++)
          acc[i][j] = __builtin_amdgcn_mfma_f32_16x16x32_bf16(af[i], bf[j], acc[i][j], 0, 0, 0);
    }
  }

#pragma unroll
  for (int i = 0; i < MI; i++) {
#pragma unroll
    for (int j = 0; j < 4; j++) {
      const int colg = bn + wn + 16 * j + l16;
      const float bb = gz.bias ? gz.bias[colg] : 0.f;
#pragma unroll
      for (int r = 0; r < 4; r++) {
        const int rowg = bm + wm + 16 * i + quad * 4 + r;
        const float v = (acc[i][j][r] + bb) * gz.scale;
        if (gz.Cb) {
          if (gz.transC) gz.Cb[(size_t)colg * 512 + rowg] = f2bf(v);
          else           gz.Cb[(size_t)rowg * 512 + colg] = f2bf(v);
        } else {
          gz.C[(size_t)rowg * 512 + colg] = v;
        }
      }
    }
  }
}

// ---------------- LayerNorm family (N=512), one wave/row ----------------
// mode 0: x = P ; mode 1: x = P + bf(R) ; mode 2: x = bf(R) + sigmoid(P)*(a'+b')
__global__ __launch_bounds__(256) void row_ln(
    const float* __restrict__ P, const ushort_t* __restrict__ R,
    const ushort_t* __restrict__ cross,
    const float* __restrict__ gamma, const float* __restrict__ beta, int gstride,
    ushort_t* __restrict__ outb, float* __restrict__ outf, int mode, int gelu)
{
  const size_t S2 = (size_t)8192 * 512;
  const int wid = threadIdx.x >> 6, lane = threadIdx.x & 63;
  const int row = blockIdx.x * 4 + wid;
  const int t = row >> 13;
  const float* g  = gamma + t * gstride;
  const float* be = beta + t * gstride;
  const float* p = P + (size_t)row * 512;
  const ushort_t* ar = nullptr;
  if (mode == 2) ar = cross + (size_t)(2 * t) * S2 + (size_t)(row & 8191) * 512;
  float v[8], s = 0.f, ss = 0.f;
#pragma unroll
  for (int j = 0; j < 8; j++) {
    const int c = lane + j * 64;
    float x = p[c];
    if (mode == 2) {
      const float sg = 1.f / (1.f + expf(-x));
      x = bf2f(R[(size_t)row * 512 + c]) + sg * (bf2f(ar[c]) + bf2f(ar[S2 + c]));
    } else if (mode == 1) {
      x += bf2f(R[(size_t)row * 512 + c]);
    }
    v[j] = x; s += x; ss += x * x;
  }
#pragma unroll
  for (int off = 32; off > 0; off >>= 1) {
    s  += __shfl_xor(s,  off, 64);
    ss += __shfl_xor(ss, off, 64);
  }
  const float mean = s * (1.f / 512.f);
  const float var  = ss * (1.f / 512.f) - mean * mean;
  const float rstd = rsqrtf(var + 1e-5f);
#pragma unroll
  for (int j = 0; j < 8; j++) {
    const int c = lane + j * 64;
    float y = g[c] * ((v[j] - mean) * rstd) + be[c];
    if (gelu) y = 0.5f * y * (1.f + erff(y * 0.70710678118f));
    if (outb) outb[(size_t)row * 512 + c] = f2bf(y);
    else      outf[(size_t)row * 512 + c] = y;
  }
}

// ---------------- logit projection: GELU(LN(sigmoid(x) @ W + b)); N=256 ----------------
__global__ __launch_bounds__(256) void lproj(
    const float* __restrict__ logits, int F,
    const float* __restrict__ W, const float* __restrict__ bias,
    const float* __restrict__ gamma, const float* __restrict__ beta,
    ushort_t* __restrict__ out)
{
  const int wid = threadIdx.x >> 6, lane = threadIdx.x & 63;
  const int row = blockIdx.x * 4 + wid;
  float sg[16];
  for (int f = 0; f < F; f++)
    sg[f] = 1.f / (1.f + expf(-logits[(size_t)row * F + f]));
  float v[4], s = 0.f, ss = 0.f;
#pragma unroll
  for (int j = 0; j < 4; j++) {
    const int c = lane + j * 64;
    float a = bias[c];
    for (int f = 0; f < F; f++) a += sg[f] * W[f * 256 + c];
    v[j] = a; s += a; ss += a * a;
  }
#pragma unroll
  for (int off = 32; off > 0; off >>= 1) {
    s  += __shfl_xor(s,  off, 64);
    ss += __shfl_xor(ss, off, 64);
  }
  const float mean = s * (1.f / 256.f);
  const float var  = ss * (1.f / 256.f) - mean * mean;
  const float rstd = rsqrtf(var + 1e-5f);
#pragma unroll
  for (int j = 0; j < 4; j++) {
    const int c = lane + j * 64;
    float y = gamma[c] * ((v[j] - mean) * rstd) + beta[c];
    y = 0.5f * y * (1.f + erff(y * 0.70710678118f));
    out[(size_t)row * 256 + c] = f2bf(y);
  }
}

// cb_z = bv_z @ Wo_z + bo_z  (f32), grid (2,1,4)
__global__ __launch_bounds__(256) void bias_combine(
    const float* __restrict__ mha_in_b, const float* __restrict__ mha_out_W,
    const float* __restrict__ mha_out_b, float* __restrict__ cb)
{
  const int z = blockIdx.z;
  const float* bv = mha_in_b + z * 1536 + 1024;
  const float* Wo = mha_out_W + (size_t)z * 512 * 512;
  const int n = blockIdx.x * 256 + threadIdx.x;
  float a = mha_out_b[z * 512 + n];
  for (int k = 0; k < 512; k++) a += bv[k] * Wo[k * 512 + n];
  cb[z * 512 + n] = a;
}

// transpose-convert: out_bf16[N,K] = in_f32[K,N];  grid (N/32, K/32, z)
__global__ __launch_bounds__(256) void tconv(
    const float* __restrict__ in, size_t in_z,
    ushort_t* __restrict__ out, size_t out_z, int K, int N)
{
  __shared__ float t[32][33];
  in  += blockIdx.z * in_z;
  out += blockIdx.z * out_z;
  const int n0 = blockIdx.x * 32, k0 = blockIdx.y * 32;
  const int tx = threadIdx.x & 31, ty = threadIdx.x >> 5;
#pragma unroll
  for (int r = 0; r < 32; r += 8)
    t[ty + r][tx] = in[(size_t)(k0 + ty + r) * N + n0 + tx];
  __syncthreads();
#pragma unroll
  for (int r = 0; r < 32; r += 8)
    out[(size_t)(n0 + ty + r) * K + k0 + tx] = f2bf(t[tx][ty + r]);
}

// Wv slice convert: out[z][k][j] = bf16(mha_in_W[z][k][1024+j]); grid (1024,1,4)
__global__ __launch_bounds__(256) void conv_wv(const float* __restrict__ in, ushort_t* __restrict__ out) {
  const int z = blockIdx.z;
  const int idx = blockIdx.x * 256 + threadIdx.x;
  const int r = idx >> 9, c = idx & 511;
  out[(size_t)z * 262144 + idx] = f2bf(in[(size_t)z * 786432 + (size_t)r * 1536 + 1024 + c]);
}

// three f32->bf16 batch; grid (8192, 3)
__global__ __launch_bounds__(256) void conv_x3(
    const float* __restrict__ a, const float* __restrict__ b,
    const float* __restrict__ c, ushort_t* __restrict__ out)
{
  const float* src = (blockIdx.y == 0) ? a : (blockIdx.y == 1) ? b : c;
  const size_t i = (size_t)blockIdx.x * 256 + threadIdx.x;
  const float4 f = ((const float4*)src)[i];
  ushort4 o;
  o.x = f2bf(f.x); o.y = f2bf(f.y); o.z = f2bf(f.z); o.w = f2bf(f.w);
  ((ushort4*)(out + (size_t)blockIdx.y * 8192 * 1024))[i] = o;
}

extern "C" void kernel_launch(void* const* d_in, const int* in_sizes, int n_in,
                              void* d_out, int out_size, void* d_ws, size_t ws_size,
                              hipStream_t stream)
{
  const float* verb_hidden   = (const float*)d_in[0];
  const float* verb_logits   = (const float*)d_in[1];
  const float* inst_hidden   = (const float*)d_in[2];
  const float* inst_logits   = (const float*)d_in[3];
  const float* target_hidden = (const float*)d_in[4];
  const float* target_logits = (const float*)d_in[5];
  const float* hp_W  = (const float*)d_in[6];
  const float* hp_b  = (const float*)d_in[7];
  const float* hp_g  = (const float*)d_in[8];
  const float* hp_be = (const float*)d_in[9];
  const float* lp_W_verb   = (const float*)d_in[10];
  const float* lp_b_verb   = (const float*)d_in[11];
  const float* lp_W_inst   = (const float*)d_in[12];
  const float* lp_b_inst   = (const float*)d_in[13];
  const float* lp_W_target = (const float*)d_in[14];
  const float* lp_b_target = (const float*)d_in[15];
  const float* lp_g  = (const float*)d_in[16];
  const float* lp_be = (const float*)d_in[17];
  const float* mha_in_W  = (const float*)d_in[18];
  const float* mha_in_b  = (const float*)d_in[19];
  const float* mha_out_W = (const float*)d_in[20];
  const float* mha_out_b = (const float*)d_in[21];
  const float* n1_g  = (const float*)d_in[22];
  const float* n1_be = (const float*)d_in[23];
  const float* n2_g  = (const float*)d_in[24];
  const float* n2_be = (const float*)d_in[25];
  const float* gate_W = (const float*)d_in[26];
  const float* gate_b = (const float*)d_in[27];
  const float* fus_W1 = (const float*)d_in[28];
  const float* fus_b1 = (const float*)d_in[29];
  const float* fus_g1 = (const float*)d_in[30];
  const float* fus_ge1= (const float*)d_in[31];
  const float* fus_W2 = (const float*)d_in[32];
  const float* fus_b2 = (const float*)d_in[33];
  const float* fus_g2 = (const float*)d_in[34];
  const float* fus_ge2= (const float*)d_in[35];

  char* w = (char*)d_ws;
  const size_t S2 = (size_t)8192 * 512;         // elems per 8192x512 matrix
  // region A (48MB): xbf (stage A) -> crossbf (6 x 8MB bf16) -> gbf(8MB)
  ushort_t* xbf     = (ushort_t*)(w + 0);
  ushort_t* crossbf = (ushort_t*)(w + 0);
  ushort_t* gbf     = (ushort_t*)(w + 0);
  float*    Pbig    = (float*)(w + 50331648);    // 48MB f32 (24576x512)
  ushort_t* hbf     = (ushort_t*)(w + 100663296);// 24MB: hbf, later fbf
  ushort_t* fbf     = (ushort_t*)(w + 100663296);
  ushort_t* ebf     = (ushort_t*)(w + 125829120);// 24MB
  ushort_t* lbf     = (ushort_t*)(w + 150994944);// 12MB (3 x 8192x256)
  char* wp = w + 163577856;
  ushort_t* hpWt   = (ushort_t*)(wp);            // 3x512x1024
  ushort_t* gateWt = (ushort_t*)(wp + 3145728);  // 3x512x1024
  ushort_t* fusW1t = (ushort_t*)(wp + 6291456);  // 512x2304
  ushort_t* fusW2t = (ushort_t*)(wp + 8650752);  // 512x512
  ushort_t* WoT    = (ushort_t*)(wp + 9175040);  // 4x512x512
  ushort_t* Wvbf   = (ushort_t*)(wp + 11272192); // 4x512x512
  ushort_t* CWt    = (ushort_t*)(wp + 13369344); // 4x512x512
  float*    cb     = (float*)(wp + 15466496);    // 4x512 f32

  dim3 blk(256);

  // ---- conversions ----
  conv_x3<<<dim3(8192, 3), blk, 0, stream>>>(verb_hidden, inst_hidden, target_hidden, xbf);
  conv_wv<<<dim3(1024, 1, 4), blk, 0, stream>>>(mha_in_W, Wvbf);
  tconv<<<dim3(16, 32, 3), blk, 0, stream>>>(hp_W,   524288, hpWt,   524288, 1024, 512);
  tconv<<<dim3(16, 32, 3), blk, 0, stream>>>(gate_W, 524288, gateWt, 524288, 1024, 512);
  tconv<<<dim3(16, 72, 1), blk, 0, stream>>>(fus_W1, 0, fusW1t, 0, 2304, 512);
  tconv<<<dim3(16, 16, 1), blk, 0, stream>>>(fus_W2, 0, fusW2t, 0, 512, 512);
  tconv<<<dim3(16, 16, 4), blk, 0, stream>>>(mha_out_W, 262144, WoT, 262144, 512, 512);
  bias_combine<<<dim3(2, 1, 4), blk, 0, stream>>>(mha_in_b, mha_out_W, mha_out_b, cb);

  // ---- fold: CWt_z = (Wv_z @ Wo_z)^T bf16, written transposed ----
  {
    GemmArgs ga{};
    for (int z = 0; z < 4; z++) {
      GemmZ& g = ga.z[z];
      g.Cb = CWt + (size_t)z * 262144; g.transC = 1; g.scale = 1.f; g.nseg = 1;
      g.seg[0] = {Wvbf + (size_t)z * 262144, WoT + (size_t)z * 262144, 512, 512, 512};
    }
    gemm_bt<128><<<dim3(4, 4, 4), blk, 0, stream>>>(ga);
  }

  // ---- stage A: P = x_t @ hp_W_t + b (z=3), then h = GELU(LN(P)) ----
  {
    GemmArgs ga{};
    for (int z = 0; z < 3; z++) {
      GemmZ& g = ga.z[z];
      g.C = Pbig + (size_t)z * S2; g.bias = hp_b + z * 512; g.scale = 1.f; g.nseg = 1;
      g.seg[0] = {xbf + (size_t)z * 8192 * 1024, hpWt + (size_t)z * 524288, 1024, 1024, 1024};
    }
    gemm_bt<128><<<dim3(64, 4, 3), blk, 0, stream>>>(ga);
  }
  row_ln<<<6144, blk, 0, stream>>>(Pbig, nullptr, nullptr, hp_g, hp_be, 512,
                                   hbf, nullptr, 0, 1);

  // ---- stage B: logit projections ----
  lproj<<<2048, blk, 0, stream>>>(verb_logits, 10, lp_W_verb, lp_b_verb,
      lp_g + 0,   lp_be + 0,   lbf);
  lproj<<<2048, blk, 0, stream>>>(inst_logits, 6, lp_W_inst, lp_b_inst,
      lp_g + 256, lp_be + 256, lbf + (size_t)8192 * 256);
  lproj<<<2048, blk, 0, stream>>>(target_logits, 15, lp_W_target, lp_b_target,
      lp_g + 512, lp_be + 512, lbf + (size_t)2 * 8192 * 256);

  // ---- stage C: e = LN(h + h @ CW0 + cb0), batched M=24576 ----
  {
    GemmArgs ga{};
    GemmZ& g = ga.z[0];
    g.C = Pbig; g.bias = cb; g.scale = 1.f; g.nseg = 1;
    g.seg[0] = {hbf, CWt, 512, 512, 512};
    gemm_bt<128><<<dim3(192, 4, 1), blk, 0, stream>>>(ga);
  }
  row_ln<<<6144, blk, 0, stream>>>(Pbig, hbf, nullptr, n1_g, n1_be, 512,
                                   ebf, nullptr, 1, 0);

  // ---- cross attention: z=6, a' = 0.5*(e_src @ CW_mod + cb_mod), bf16 out ----
  const int mods[3][2] = {{1, 2}, {1, 3}, {2, 3}};
  const int srcs[3][2] = {{1, 2}, {0, 2}, {0, 1}};
  {
    GemmArgs ga{};
    for (int t = 0; t < 3; t++)
      for (int u = 0; u < 2; u++) {
        GemmZ& g = ga.z[2 * t + u];
        g.Cb = crossbf + (size_t)(2 * t + u) * S2; g.transC = 0;
        g.bias = cb + mods[t][u] * 512; g.scale = 0.5f; g.nseg = 1;
        g.seg[0] = {ebf + (size_t)srcs[t][u] * S2, CWt + (size_t)mods[t][u] * 262144, 512, 512, 512};
      }
    gemm_bt<128><<<dim3(64, 4, 6), blk, 0, stream>>>(ga);
  }

  // ---- gate: z=3, P = e@Wtop + a'@Wbot + b'@Wbot + bg (3 segments) ----
  {
    GemmArgs ga{};
    for (int t = 0; t < 3; t++) {
      GemmZ& g = ga.z[t];
      g.C = Pbig + (size_t)t * S2; g.bias = gate_b + t * 512; g.scale = 1.f; g.nseg = 3;
      const ushort_t* Wt = gateWt + (size_t)t * 524288;
      g.seg[0] = {ebf + (size_t)t * S2,           Wt,       512, 1024, 512};
      g.seg[1] = {crossbf + (size_t)(2 * t) * S2, Wt + 512, 512, 1024, 512};
      g.seg[2] = {crossbf + (size_t)(2 * t + 1) * S2, Wt + 512, 512, 1024, 512};
    }
    gemm_bt<128><<<dim3(64, 4, 3), blk, 0, stream>>>(ga);
  }
  // fuse: f = LN(e + sigmoid(P)*(a'+b')) -> fbf
  row_ln<<<6144, blk, 0, stream>>>(Pbig, ebf, crossbf, n2_g, n2_be, 512,
                                   fbf, nullptr, 2, 0);

  // ---- fusion head: fus1 = 6-segment GEMM over [f0,f1,f2,l0,l1,l2] ----
  {
    GemmArgs ga{};
    GemmZ& g = ga.z[0];
    g.C = Pbig; g.bias = fus_b1; g.scale = 1.f; g.nseg = 6;
    g.seg[0] = {fbf,                         fusW1t,        512, 2304, 512};
    g.seg[1] = {fbf + S2,                    fusW1t + 512,  512, 2304, 512};
    g.seg[2] = {fbf + 2 * S2,                fusW1t + 1024, 512, 2304, 512};
    g.seg[3] = {lbf,                         fusW1t + 1536, 256, 2304, 256};
    g.seg[4] = {lbf + (size_t)8192 * 256,    fusW1t + 1792, 256, 2304, 256};
    g.seg[5] = {lbf + (size_t)2 * 8192 * 256,fusW1t + 2048, 256, 2304, 256};
    gemm_bt<64><<<dim3(128, 4, 1), blk, 0, stream>>>(ga);
  }
  row_ln<<<2048, blk, 0, stream>>>(Pbig, nullptr, nullptr, fus_g1, fus_ge1, 0,
                                   gbf, nullptr, 0, 1);
  {
    GemmArgs ga{};
    GemmZ& g = ga.z[0];
    g.C = Pbig; g.bias = fus_b2; g.scale = 1.f; g.nseg = 1;
    g.seg[0] = {gbf, fusW2t, 512, 512, 512};
    gemm_bt<64><<<dim3(128, 4, 1), blk, 0, stream>>>(ga);
  }
  row_ln<<<2048, blk, 0, stream>>>(Pbig, nullptr, nullptr, fus_g2, fus_ge2, 0,
                                   nullptr, (float*)d_out, 0, 0);
}

// Round 4
// 669.806 us; speedup vs baseline: 1.6376x; 1.0208x over previous
//
#include <hip/hip_runtime.h>
#include <math.h>

typedef unsigned short ushort_t;
using short8  = __attribute__((ext_vector_type(8))) short;
using floatx4 = __attribute__((ext_vector_type(4))) float;

__device__ __forceinline__ ushort_t f2bf(float f) {
  unsigned u = __builtin_bit_cast(unsigned, f);
  u = (u + 0x7fffu + ((u >> 16) & 1u)) >> 16;
  return (ushort_t)u;
}
__device__ __forceinline__ float bf2f(ushort_t u) {
  unsigned v = ((unsigned)u) << 16;
  return __builtin_bit_cast(float, v);
}

__device__ __forceinline__ void load_lds16(const ushort_t* g, ushort_t* l) {
  __builtin_amdgcn_global_load_lds(
      (const __attribute__((address_space(1))) unsigned int*)g,
      (__attribute__((address_space(3))) unsigned int*)l, 16, 0, 0);
}

// ---------------- segmented batched GEMM (bf16 in, bf16 out) ----------------
// C[M,512] = (sum_s A_s[M,Ks] @ W_s^T + bias) * scale ; W_s stored [512,Ks] bf16
struct Seg { const ushort_t* A; const ushort_t* W; int lda, ldw, K; };
struct GemmZ {
  ushort_t* Cb;        // row-major [row*512+col] bf16 (may be null)
  ushort_t* CbT;       // transposed [col*512+row] bf16 (may be null; folds only, M=512)
  const float* bias;
  float scale; int nseg; int mmax;   // blocks with blockIdx.x >= mmax exit
  Seg seg[6];
};
struct GemmArgs { GemmZ z[9]; };

template <int BM>
__global__ __launch_bounds__(256) void gemm_bt(GemmArgs ga) {
  const GemmZ& gz = ga.z[blockIdx.z];
  if ((int)blockIdx.x >= gz.mmax) return;
  __shared__ ushort_t As[BM * 32];
  __shared__ ushort_t Bs[128 * 32];
  const int tid = threadIdx.x;
  const int wid = tid >> 6, lane = tid & 63, quad = lane >> 4, l16 = lane & 15;
  const int bm = blockIdx.x * BM, bn = blockIdx.y * 128;
  constexpr int MI = BM / 32;
  const int wm = (wid & 1) * (BM / 2), wn = (wid >> 1) * 64;
  floatx4 acc[MI][4] = {};
  const int srow = tid >> 2, scol = (tid & 3) * 8;
  ushort_t* aL = As + tid * 8;
  ushort_t* bL = Bs + tid * 8;

  for (int s = 0; s < gz.nseg; s++) {
    const Seg sg = gz.seg[s];
    const ushort_t* aG = sg.A + (size_t)(bm + srow) * sg.lda + scol;
    const ushort_t* bG = sg.W + (size_t)(bn + srow) * sg.ldw + scol;
    const size_t astep = (size_t)64 * sg.lda;
    const size_t bstep = (size_t)64 * sg.ldw;
    for (int k0 = 0; k0 < sg.K; k0 += 32) {
      __syncthreads();
      load_lds16(aG + k0, aL);
      if (BM == 128) load_lds16(aG + k0 + astep, aL + 2048);
      load_lds16(bG + k0, bL);
      load_lds16(bG + k0 + bstep, bL + 2048);
      __syncthreads();
      short8 af[MI], bf[4];
#pragma unroll
      for (int i = 0; i < MI; i++)
        af[i] = *(const short8*)&As[(wm + 16 * i + l16) * 32 + quad * 8];
#pragma unroll
      for (int j = 0; j < 4; j++)
        bf[j] = *(const short8*)&Bs[(wn + 16 * j + l16) * 32 + quad * 8];
#pragma unroll
      for (int i = 0; i < MI; i++)
#pragma unroll
        for (int j = 0; j < 4; j++)
          acc[i][j] = __builtin_amdgcn_mfma_f32_16x16x32_bf16(af[i], bf[j], acc[i][j], 0, 0, 0);
    }
  }

#pragma unroll
  for (int i = 0; i < MI; i++) {
#pragma unroll
    for (int j = 0; j < 4; j++) {
      const int colg = bn + wn + 16 * j + l16;
      const float bb = gz.bias ? gz.bias[colg] : 0.f;
#pragma unroll
      for (int r = 0; r < 4; r++) {
        const int rowg = bm + wm + 16 * i + quad * 4 + r;
        const float v = (acc[i][j][r] + bb) * gz.scale;
        const ushort_t bo = f2bf(v);
        if (gz.Cb)  gz.Cb[(size_t)rowg * 512 + colg] = bo;
        if (gz.CbT) gz.CbT[(size_t)colg * 512 + rowg] = bo;
      }
    }
  }
}

// ---------------- LayerNorm family (N=512), one wave/row, bf16 preacts ----------------
// mode 0: x = P ; mode 1: x = P + R ; mode 2: x = R + sigmoid(P)*(a'+b')
__global__ __launch_bounds__(256) void row_ln(
    const ushort_t* __restrict__ P, const ushort_t* __restrict__ R,
    const ushort_t* __restrict__ cross,
    const float* __restrict__ gamma, const float* __restrict__ beta, int gstride,
    ushort_t* __restrict__ outb, float* __restrict__ outf, int mode, int gelu)
{
  const size_t S2 = (size_t)8192 * 512;
  const int wid = threadIdx.x >> 6, lane = threadIdx.x & 63;
  const int row = blockIdx.x * 4 + wid;
  const int t = row >> 13;
  const float* g  = gamma + t * gstride;
  const float* be = beta + t * gstride;
  const ushort_t* p = P + (size_t)row * 512;
  const ushort_t* ar = nullptr;
  if (mode == 2) ar = cross + (size_t)(2 * t) * S2 + (size_t)(row & 8191) * 512;
  float v[8], s = 0.f, ss = 0.f;
#pragma unroll
  for (int j = 0; j < 8; j++) {
    const int c = lane + j * 64;
    float x = bf2f(p[c]);
    if (mode == 2) {
      const float sg = 1.f / (1.f + expf(-x));
      x = bf2f(R[(size_t)row * 512 + c]) + sg * (bf2f(ar[c]) + bf2f(ar[S2 + c]));
    } else if (mode == 1) {
      x += bf2f(R[(size_t)row * 512 + c]);
    }
    v[j] = x; s += x; ss += x * x;
  }
#pragma unroll
  for (int off = 32; off > 0; off >>= 1) {
    s  += __shfl_xor(s,  off, 64);
    ss += __shfl_xor(ss, off, 64);
  }
  const float mean = s * (1.f / 512.f);
  const float var  = ss * (1.f / 512.f) - mean * mean;
  const float rstd = rsqrtf(var + 1e-5f);
#pragma unroll
  for (int j = 0; j < 8; j++) {
    const int c = lane + j * 64;
    float y = g[c] * ((v[j] - mean) * rstd) + be[c];
    if (gelu) y = 0.5f * y * (1.f + erff(y * 0.70710678118f));
    if (outb) outb[(size_t)row * 512 + c] = f2bf(y);
    else      outf[(size_t)row * 512 + c] = y;
  }
}

// ---------------- merged logit projections: GELU(LN(sigmoid(x)@W + b)); grid (2048,3) ----------------
__global__ __launch_bounds__(256) void lproj3(
    const float* __restrict__ vl, const float* __restrict__ il, const float* __restrict__ tl,
    const float* __restrict__ Wv, const float* __restrict__ bv,
    const float* __restrict__ Wi, const float* __restrict__ bi,
    const float* __restrict__ Wt, const float* __restrict__ bt,
    const float* __restrict__ lp_g, const float* __restrict__ lp_be,
    ushort_t* __restrict__ out)
{
  const int set = blockIdx.y;
  const float* logits = set == 0 ? vl : set == 1 ? il : tl;
  const int F = set == 0 ? 10 : set == 1 ? 6 : 15;
  const float* W    = set == 0 ? Wv : set == 1 ? Wi : Wt;
  const float* bias = set == 0 ? bv : set == 1 ? bi : bt;
  const float* gamma = lp_g + set * 256;
  const float* beta  = lp_be + set * 256;
  ushort_t* o = out + (size_t)set * 8192 * 256;
  const int wid = threadIdx.x >> 6, lane = threadIdx.x & 63;
  const int row = blockIdx.x * 4 + wid;
  float sg[16];
  for (int f = 0; f < F; f++)
    sg[f] = 1.f / (1.f + expf(-logits[(size_t)row * F + f]));
  float v[4], s = 0.f, ss = 0.f;
#pragma unroll
  for (int j = 0; j < 4; j++) {
    const int c = lane + j * 64;
    float a = bias[c];
    for (int f = 0; f < F; f++) a += sg[f] * W[f * 256 + c];
    v[j] = a; s += a; ss += a * a;
  }
#pragma unroll
  for (int off = 32; off > 0; off >>= 1) {
    s  += __shfl_xor(s,  off, 64);
    ss += __shfl_xor(ss, off, 64);
  }
  const float mean = s * (1.f / 256.f);
  const float var  = ss * (1.f / 256.f) - mean * mean;
  const float rstd = rsqrtf(var + 1e-5f);
#pragma unroll
  for (int j = 0; j < 4; j++) {
    const int c = lane + j * 64;
    float y = gamma[c] * ((v[j] - mean) * rstd) + beta[c];
    y = 0.5f * y * (1.f + erff(y * 0.70710678118f));
    o[(size_t)row * 256 + c] = f2bf(y);
  }
}

// ---------------- prep: all conversions + cb, one launch ----------------
struct PrepArgs {
  const float *vh, *ih, *th;
  const float *mha_in_W, *mha_out_W, *mha_in_b, *mha_out_b;
  const float *hp_W, *gate_W, *fus_W1, *fus_W2;
  ushort_t *xbf, *Wvbf, *hpWt, *gateWt, *fusW1t, *fusW2t, *WoT;
  float *cb;
};

__global__ __launch_bounds__(256) void prep(PrepArgs pa) {
  __shared__ float tsh[32][33];
  const int b = blockIdx.x, tid = threadIdx.x;
  if (b < 24576) {                       // hidden f32 -> bf16
    const int mat = b >> 13, blk = b & 8191;
    const float* src = mat == 0 ? pa.vh : mat == 1 ? pa.ih : pa.th;
    const size_t i = (size_t)blk * 256 + tid;
    const float4 f = ((const float4*)src)[i];
    ushort4 o; o.x = f2bf(f.x); o.y = f2bf(f.y); o.z = f2bf(f.z); o.w = f2bf(f.w);
    ((ushort4*)(pa.xbf + (size_t)mat * 8192 * 1024))[i] = o;
    return;
  }
  if (b < 28672) {                       // Wv slice -> bf16
    const int u = b - 24576, z = u >> 10, blk = u & 1023;
    const int idx = blk * 256 + tid, r = idx >> 9, c = idx & 511;
    pa.Wvbf[(size_t)z * 262144 + idx] =
        f2bf(pa.mha_in_W[(size_t)z * 786432 + (size_t)r * 1536 + 1024 + c]);
    return;
  }
  if (b >= 34176) {                      // cb_z = bv_z @ Wo_z + bo_z
    const int u2 = b - 34176, z = u2 >> 1, part = u2 & 1;
    const int n = part * 256 + tid;
    const float* bv = pa.mha_in_b + z * 1536 + 1024;
    const float* Wo = pa.mha_out_W + (size_t)z * 262144;
    float a = pa.mha_out_b[z * 512 + n];
    for (int k = 0; k < 512; k++) a += bv[k] * Wo[(size_t)k * 512 + n];
    pa.cb[z * 512 + n] = a;
    return;
  }
  // transpose-converts
  const float* tin; ushort_t* tout; int K, N, u; size_t izs, ozs;
  if (b < 30208)      { u = b - 28672; tin = pa.hp_W;      tout = pa.hpWt;   K = 1024; N = 512; izs = 524288; ozs = 524288; }
  else if (b < 31744) { u = b - 30208; tin = pa.gate_W;    tout = pa.gateWt; K = 1024; N = 512; izs = 524288; ozs = 524288; }
  else if (b < 32896) { u = b - 31744; tin = pa.fus_W1;    tout = pa.fusW1t; K = 2304; N = 512; izs = 0;      ozs = 0; }
  else if (b < 33152) { u = b - 32896; tin = pa.fus_W2;    tout = pa.fusW2t; K = 512;  N = 512; izs = 0;      ozs = 0; }
  else                { u = b - 33152; tin = pa.mha_out_W; tout = pa.WoT;    K = 512;  N = 512; izs = 262144; ozs = 262144; }
  const int nbx = N / 32, perz = nbx * (K / 32);
  const int z = u / perz, rem = u % perz, bx = rem % nbx, by = rem / nbx;
  tin += (size_t)z * izs; tout += (size_t)z * ozs;
  const int n0 = bx * 32, k0 = by * 32;
  const int tx = tid & 31, ty = tid >> 5;
#pragma unroll
  for (int r = 0; r < 32; r += 8)
    tsh[ty + r][tx] = tin[(size_t)(k0 + ty + r) * N + n0 + tx];
  __syncthreads();
#pragma unroll
  for (int r = 0; r < 32; r += 8)
    tout[(size_t)(n0 + ty + r) * K + k0 + tx] = f2bf(tsh[tx][ty + r]);
}

// gate folded bias: bias2[t][n] = gate_b[t][n] + 0.5*sum_k (cb[m1]+cb[m2])[k] * gate_W[t][512+k][n]
__global__ __launch_bounds__(256) void bias2_k(
    const float* __restrict__ cb, const float* __restrict__ gate_W,
    const float* __restrict__ gate_b, float* __restrict__ out)
{
  const int t = blockIdx.z;
  const int m1[3] = {1, 1, 2}, m2[3] = {2, 3, 3};
  const float* c1 = cb + m1[t] * 512;
  const float* c2 = cb + m2[t] * 512;
  const float* W = gate_W + (size_t)t * 524288 + (size_t)512 * 512;
  const int n = blockIdx.x * 256 + threadIdx.x;
  float a = gate_b[t * 512 + n];
  for (int k = 0; k < 512; k++) a += 0.5f * (c1[k] + c2[k]) * W[(size_t)k * 512 + n];
  out[t * 512 + n] = a;
}

extern "C" void kernel_launch(void* const* d_in, const int* in_sizes, int n_in,
                              void* d_out, int out_size, void* d_ws, size_t ws_size,
                              hipStream_t stream)
{
  const float* verb_hidden   = (const float*)d_in[0];
  const float* verb_logits   = (const float*)d_in[1];
  const float* inst_hidden   = (const float*)d_in[2];
  const float* inst_logits   = (const float*)d_in[3];
  const float* target_hidden = (const float*)d_in[4];
  const float* target_logits = (const float*)d_in[5];
  const float* hp_W  = (const float*)d_in[6];
  const float* hp_b  = (const float*)d_in[7];
  const float* hp_g  = (const float*)d_in[8];
  const float* hp_be = (const float*)d_in[9];
  const float* lp_W_verb   = (const float*)d_in[10];
  const float* lp_b_verb   = (const float*)d_in[11];
  const float* lp_W_inst   = (const float*)d_in[12];
  const float* lp_b_inst   = (const float*)d_in[13];
  const float* lp_W_target = (const float*)d_in[14];
  const float* lp_b_target = (const float*)d_in[15];
  const float* lp_g  = (const float*)d_in[16];
  const float* lp_be = (const float*)d_in[17];
  const float* mha_in_W  = (const float*)d_in[18];
  const float* mha_in_b  = (const float*)d_in[19];
  const float* mha_out_W = (const float*)d_in[20];
  const float* mha_out_b = (const float*)d_in[21];
  const float* n1_g  = (const float*)d_in[22];
  const float* n1_be = (const float*)d_in[23];
  const float* n2_g  = (const float*)d_in[24];
  const float* n2_be = (const float*)d_in[25];
  const float* gate_W = (const float*)d_in[26];
  const float* gate_b = (const float*)d_in[27];
  const float* fus_W1 = (const float*)d_in[28];
  const float* fus_b1 = (const float*)d_in[29];
  const float* fus_g1 = (const float*)d_in[30];
  const float* fus_ge1= (const float*)d_in[31];
  const float* fus_W2 = (const float*)d_in[32];
  const float* fus_b2 = (const float*)d_in[33];
  const float* fus_g2 = (const float*)d_in[34];
  const float* fus_ge2= (const float*)d_in[35];

  char* w = (char*)d_ws;
  const size_t S2 = (size_t)8192 * 512;
  const size_t MB = 1024 * 1024;
  // region0 48MB: xbf (L1-L4) -> crossbf (L9-L10) -> gbf (L12-L13)
  ushort_t* xbf     = (ushort_t*)(w);
  ushort_t* crossbf = (ushort_t*)(w);
  ushort_t* gbf     = (ushort_t*)(w);
  ushort_t* Pbig    = (ushort_t*)(w + 48 * MB);   // 24 MB bf16 preacts (3 x S2)
  ushort_t* hbf     = (ushort_t*)(w + 72 * MB);   // 24 MB; later fbf
  ushort_t* fbf     = (ushort_t*)(w + 72 * MB);
  ushort_t* ebf     = (ushort_t*)(w + 96 * MB);   // 24 MB
  ushort_t* lbf     = (ushort_t*)(w + 120 * MB);  // 12 MB
  char* wp = w + 132 * MB;
  ushort_t* hpWt    = (ushort_t*)(wp);                 // 3x512x1024 bf16
  ushort_t* gateWt  = (ushort_t*)(wp + 3145728);       // 3x512x1024
  ushort_t* fusW1t  = (ushort_t*)(wp + 6291456);       // 512x2304
  ushort_t* fusW2t  = (ushort_t*)(wp + 8650752);       // 512x512
  ushort_t* WoT     = (ushort_t*)(wp + 9175040);       // 4x512x512
  ushort_t* Wvbf    = (ushort_t*)(wp + 11272192);      // 4x512x512
  ushort_t* CWt     = (ushort_t*)(wp + 13369344);      // 4x512x512 (CW^T)
  ushort_t* CWplain = (ushort_t*)(wp + 15466496);      // 4x512x512 (CW row-major)
  ushort_t* Gt      = (ushort_t*)(wp + 17563648);      // 6x512x512 (0.5*CW_m@Wbot_t, [n][k])
  float*    cb      = (float*)(wp + 20709376);         // 4x512 f32
  float*    bias2   = (float*)(wp + 20717568);         // 3x512 f32

  dim3 blk(256);
  const int mods[3][2] = {{1, 2}, {1, 3}, {2, 3}};
  const int srcs[3][2] = {{1, 2}, {0, 2}, {0, 1}};

  // L1: prep
  {
    PrepArgs pa;
    pa.vh = verb_hidden; pa.ih = inst_hidden; pa.th = target_hidden;
    pa.mha_in_W = mha_in_W; pa.mha_out_W = mha_out_W;
    pa.mha_in_b = mha_in_b; pa.mha_out_b = mha_out_b;
    pa.hp_W = hp_W; pa.gate_W = gate_W; pa.fus_W1 = fus_W1; pa.fus_W2 = fus_W2;
    pa.xbf = xbf; pa.Wvbf = Wvbf; pa.hpWt = hpWt; pa.gateWt = gateWt;
    pa.fusW1t = fusW1t; pa.fusW2t = fusW2t; pa.WoT = WoT; pa.cb = cb;
    prep<<<34184, blk, 0, stream>>>(pa);
  }

  // L2: fold1 — CW_z = Wv_z @ Wo_z, write both plain and transposed bf16
  {
    GemmArgs ga{};
    for (int z = 0; z < 4; z++) {
      GemmZ& g = ga.z[z];
      g.Cb = CWplain + (size_t)z * 262144; g.CbT = CWt + (size_t)z * 262144;
      g.scale = 1.f; g.nseg = 1; g.mmax = 4;
      g.seg[0] = {Wvbf + (size_t)z * 262144, WoT + (size_t)z * 262144, 512, 512, 512};
    }
    gemm_bt<128><<<dim3(4, 4, 4), blk, 0, stream>>>(ga);
  }

  // L3: folded gate biases
  bias2_k<<<dim3(2, 1, 3), blk, 0, stream>>>(cb, gate_W, gate_b, bias2);

  // L4: stage A (z=0..2) + fold2 G_{t,u} = 0.5*CW_m@Wbot_t (z=3..8, masked)
  {
    GemmArgs ga{};
    for (int z = 0; z < 3; z++) {
      GemmZ& g = ga.z[z];
      g.Cb = Pbig + (size_t)z * S2; g.bias = hp_b + z * 512;
      g.scale = 1.f; g.nseg = 1; g.mmax = 64;
      g.seg[0] = {xbf + (size_t)z * 8192 * 1024, hpWt + (size_t)z * 524288, 1024, 1024, 1024};
    }
    for (int idx = 0; idx < 6; idx++) {
      const int t = idx >> 1, u = idx & 1, m = mods[t][u];
      GemmZ& g = ga.z[3 + idx];
      g.Cb = Gt + (size_t)idx * 262144; g.scale = 0.5f; g.nseg = 1; g.mmax = 4;
      // A = Wbot_t^T (gateWt cols 512..1023), W = CW_m row-major
      g.seg[0] = {gateWt + (size_t)t * 524288 + 512, CWplain + (size_t)m * 262144, 1024, 512, 512};
    }
    gemm_bt<128><<<dim3(64, 4, 9), blk, 0, stream>>>(ga);
  }

  // L5: merged logit projections
  lproj3<<<dim3(2048, 3), blk, 0, stream>>>(verb_logits, inst_logits, target_logits,
      lp_W_verb, lp_b_verb, lp_W_inst, lp_b_inst, lp_W_target, lp_b_target,
      lp_g, lp_be, lbf);

  // L6: h = GELU(LN(P))
  row_ln<<<6144, blk, 0, stream>>>(Pbig, nullptr, nullptr, hp_g, hp_be, 512,
                                   hbf, nullptr, 0, 1);

  // L7: stage C preact = h @ CW0 + cb0 (M=24576)
  {
    GemmArgs ga{};
    GemmZ& g = ga.z[0];
    g.Cb = Pbig; g.bias = cb; g.scale = 1.f; g.nseg = 1; g.mmax = 192;
    g.seg[0] = {hbf, CWt, 512, 512, 512};
    gemm_bt<128><<<dim3(192, 4, 1), blk, 0, stream>>>(ga);
  }
  // L8: e = LN(h + P)
  row_ln<<<6144, blk, 0, stream>>>(Pbig, hbf, nullptr, n1_g, n1_be, 512,
                                   ebf, nullptr, 1, 0);

  // L9: cross (z=0..5) + gate (z=6..8) in one launch
  {
    GemmArgs ga{};
    for (int t = 0; t < 3; t++)
      for (int u = 0; u < 2; u++) {
        GemmZ& g = ga.z[2 * t + u];
        g.Cb = crossbf + (size_t)(2 * t + u) * S2;
        g.bias = cb + mods[t][u] * 512; g.scale = 0.5f; g.nseg = 1; g.mmax = 64;
        g.seg[0] = {ebf + (size_t)srcs[t][u] * S2, CWt + (size_t)mods[t][u] * 262144, 512, 512, 512};
      }
    for (int t = 0; t < 3; t++) {
      GemmZ& g = ga.z[6 + t];
      g.Cb = Pbig + (size_t)t * S2; g.bias = bias2 + t * 512;
      g.scale = 1.f; g.nseg = 3; g.mmax = 64;
      g.seg[0] = {ebf + (size_t)t * S2,           gateWt + (size_t)t * 524288, 512, 1024, 512};
      g.seg[1] = {ebf + (size_t)srcs[t][0] * S2,  Gt + (size_t)(2 * t) * 262144,     512, 512, 512};
      g.seg[2] = {ebf + (size_t)srcs[t][1] * S2,  Gt + (size_t)(2 * t + 1) * 262144, 512, 512, 512};
    }
    gemm_bt<128><<<dim3(64, 4, 9), blk, 0, stream>>>(ga);
  }

  // L10: f = LN(e + sigmoid(P)*(a'+b'))
  row_ln<<<6144, blk, 0, stream>>>(Pbig, ebf, crossbf, n2_g, n2_be, 512,
                                   fbf, nullptr, 2, 0);

  // L11: fus1 preact = [f0,f1,f2,l0,l1,l2] @ fus_W1 + b1 (6 segments)
  {
    GemmArgs ga{};
    GemmZ& g = ga.z[0];
    g.Cb = Pbig; g.bias = fus_b1; g.scale = 1.f; g.nseg = 6; g.mmax = 128;
    g.seg[0] = {fbf,                          fusW1t,        512, 2304, 512};
    g.seg[1] = {fbf + S2,                     fusW1t + 512,  512, 2304, 512};
    g.seg[2] = {fbf + 2 * S2,                 fusW1t + 1024, 512, 2304, 512};
    g.seg[3] = {lbf,                          fusW1t + 1536, 256, 2304, 256};
    g.seg[4] = {lbf + (size_t)8192 * 256,     fusW1t + 1792, 256, 2304, 256};
    g.seg[5] = {lbf + (size_t)2 * 8192 * 256, fusW1t + 2048, 256, 2304, 256};
    gemm_bt<64><<<dim3(128, 4, 1), blk, 0, stream>>>(ga);
  }
  // L12: g = GELU(LN(P))
  row_ln<<<2048, blk, 0, stream>>>(Pbig, nullptr, nullptr, fus_g1, fus_ge1, 0,
                                   gbf, nullptr, 0, 1);
  // L13: fus2 preact
  {
    GemmArgs ga{};
    GemmZ& g = ga.z[0];
    g.Cb = Pbig; g.bias = fus_b2; g.scale = 1.f; g.nseg = 1; g.mmax = 128;
    g.seg[0] = {gbf, fusW2t, 512, 512, 512};
    gemm_bt<64><<<dim3(128, 4, 1), blk, 0, stream>>>(ga);
  }
  // L14: out = LN(P), f32
  row_ln<<<2048, blk, 0, stream>>>(Pbig, nullptr, nullptr, fus_g2, fus_ge2, 0,
                                   nullptr, (float*)d_out, 0, 0);
}